// Round 3
// baseline (367.197 us; speedup 1.0000x reference)
//
#include <hip/hip_runtime.h>
#include <hip/hip_bf16.h>

// Problem constants
#define NT 8192            // tokens
#define NQB 6              // qubits
#define NL 2               // layers
// Attention kernel tiling
#define JSPLIT 16
#define JSLICE (NT / JSPLIT)     // 512 keys per block
#define CHUNK 64                 // keys staged per LDS chunk
#define NCHUNK (JSLICE / CHUNK)  // 8
#define IPW 32                   // query rows per wave (2 rowtiles of 16)
#define WPB 4                    // waves per block
#define IPB (IPW * WPB)          // 128 rows per block
#define NBI (NT / IPB)           // 64 i-blocks

typedef __bf16 bf16x8 __attribute__((ext_vector_type(8)));
typedef float f32x4 __attribute__((ext_vector_type(4)));

static __device__ __forceinline__ unsigned int pack_bf2(float a, float b) {
  unsigned short lo = __builtin_bit_cast(unsigned short, __float2bfloat16(a));
  unsigned short hi = __builtin_bit_cast(unsigned short, __float2bfloat16(b));
  return (unsigned int)lo | ((unsigned int)hi << 16);
}

// one CNOT's index map: src(p) = p ^ (bit_c(p) ? mask_t : 0)  (an involution)
static __device__ __forceinline__ int cnot_src(int p, int q) {
  const int mc = 1 << (5 - q);
  const int mt = 1 << (5 - ((q + 1) % NQB));
  return (p & mc) ? (p ^ mt) : p;
}

// ---------------------------------------------------------------------------
// Kernel 1: statevector prep, product-state form. One wave per (token, set);
// lane = basis state.  Sequence per reference:
//   [RY(x_q) embed][l0: RY,RZ][ring1][l1: RY,RZ][ring2]
// Facts used:
//  - single-qubit gates preserve product states; RY*RY = RY(sum)
//  - state after l0 = prod_q u_q, u_q = (cos t_q e^{-ib_q/2}, sin t_q e^{+ib_q/2}),
//    t_q = (x_q + p[0][q][0])/2, b_q = p[0][q][1]
//  - CNOT ring = fixed index permutation sigma; after ring1:
//    amp[lane] = prod-state evaluated at m = sigma(lane)  (no shuffles)
//  - l1 RZs commute past other-qubit RYs -> one combined phase rotation
//  - ring2 folds into the store index inv = sigma^{-1}(lane)
// ---------------------------------------------------------------------------
__global__ __launch_bounds__(256) void prep_kernel(
    const float* __restrict__ x, const float* __restrict__ pq,
    const float* __restrict__ pk, const float* __restrict__ pv,
    unsigned int* __restrict__ Are, unsigned int* __restrict__ Bk,
    float4* __restrict__ V4)
{
  const int wid  = blockIdx.x * 4 + (threadIdx.x >> 6);
  const int lane = threadIdx.x & 63;
  const int set  = wid >> 13;          // / 8192
  const int tok  = wid & (NT - 1);
  const float* pp = (set == 0) ? pq : ((set == 1) ? pk : pv);

  // sigma(l) = src_0(src_1(...src_5(l)))   [final[l] = old[sigma(l)]]
  int m = lane;
#pragma unroll
  for (int q = 5; q >= 0; --q) m = cnot_src(m, q);
  // sigma^{-1}(l) = src_5(src_4(...src_0(l)))  (each src is an involution)
  int inv = lane;
#pragma unroll
  for (int q = 0; q < 6; ++q) inv = cnot_src(inv, q);

  // product state (through layer-0) evaluated at index m
  float R = 1.f, phi = 0.f;
#pragma unroll
  for (int q = 0; q < 6; ++q) {
    float s, c;
    __sincosf(0.5f * (x[tok * NQB + q] + pp[q * 2 + 0]), &s, &c);
    const float bh = 0.5f * pp[q * 2 + 1];
    if ((m >> (5 - q)) & 1) { R *= s; phi += bh; }
    else                    { R *= c; phi -= bh; }
  }
  float sp, cp;
  __sincosf(phi, &sp, &cp);
  float re = R * cp, im = R * sp;

  // layer-1 RYs (entangled now -> shuffles), qubit order preserved
#pragma unroll
  for (int q = 0; q < 6; ++q) {
    const int mask = 1 << (5 - q);
    float s, c;
    __sincosf(0.5f * pp[2 * NQB + q * 2 + 0], &s, &c);
    const float pre = __shfl_xor(re, mask, 64);
    const float pim = __shfl_xor(im, mask, 64);
    const float se = (lane & mask) ? s : -s;
    re = fmaf(se, pre, c * re);
    im = fmaf(se, pim, c * im);
  }
  // layer-1 RZs combined into one phase per lane
  float phi2 = 0.f;
#pragma unroll
  for (int q = 0; q < 6; ++q) {
    const float bh = 0.5f * pp[2 * NQB + q * 2 + 1];
    phi2 += (lane & (1 << (5 - q))) ? bh : -bh;
  }
  float s2, c2;
  __sincosf(phi2, &s2, &c2);
  const float fre = re * c2 - im * s2;
  const float fim = re * s2 + im * c2;

  if (set == 0) {
    Are[tok * 64 + inv] = pack_bf2(fre, fim);     // [qr, qi]
  } else if (set == 1) {
    Bk[tok * 64 + inv] = pack_bf2(fre, fim);      // [kr, ki]
  } else {
    const float prob = fre * fre + fim * fim;     // prob of final basis index 'inv'
    float vq[NQB];
#pragma unroll
    for (int q = 0; q < NQB; ++q) {
      float v = (inv & (1 << (5 - q))) ? -prob : prob;  // sign = 1-2*bit
#pragma unroll
      for (int off = 1; off < 64; off <<= 1) v += __shfl_xor(v, off, 64);
      vq[q] = v;
    }
    if (lane == 0) {
      V4[tok * 2 + 0] = make_float4(vq[0], vq[1], vq[2], vq[3]);
      V4[tok * 2 + 1] = make_float4(vq[4], vq[5], 0.f, 0.f);
    }
  }
}

// ---------------------------------------------------------------------------
// Kernel 2: fused swap-test attention.
//  - block: 4 waves x 32 query rows = 128 rows; grid = 64 i-blocks x 16 j-slices
//    (1024 blocks = 4 blocks/CU; launch_bounds(256,4) -> 16 waves/CU)
//  - f = Re^2+Im^2 in [0,1] => softmax needs no max-shift; w = exp(f)
// MFMA 16x16x32 bf16 layouts (guide-verified):
//   A: row = lane&15, k = (lane>>4)*8 + j
//   B: col = lane&15, k = (lane>>4)*8 + j
//   D: col = lane&15, row = (lane>>4)*4 + reg
// ---------------------------------------------------------------------------
__global__ __launch_bounds__(256, 4) void attn_kernel(
    const uint4* __restrict__ Are, const uint4* __restrict__ Bk,
    const float4* __restrict__ V4, float* __restrict__ part)
{
  __shared__ uint4 kbuf[CHUNK * 17];   // row stride 17 uint4 = 272B
  __shared__ float4 vbuf[CHUNK * 2];   // 8 floats per key (6 used)

  const int tid  = threadIdx.x;
  const int lane = tid & 63;
  const int wave = tid >> 6;
  const int col  = lane & 15;
  const int quad = lane >> 4;

  const int ib = blockIdx.x & (NBI - 1);
  const int js = blockIdx.x / NBI;
  const int ibase = ib * IPB + wave * IPW;
  const int jbase0 = js * JSLICE;

  // A fragments for this wave's 32 rows, kept in registers for the whole sweep.
  // aIm derived in-register: (qr,qi) -> (qi,-qr) per packed u32.
  bf16x8 aRe[2][4], aIm[2][4];
#pragma unroll
  for (int rt = 0; rt < 2; ++rt) {
    const int row = ibase + rt * 16 + col;
    const uint4* pr = Are + row * 16 + quad;   // row = 16 uint4 (256B)
#pragma unroll
    for (int s = 0; s < 4; ++s) {
      const uint4 u = pr[s * 4];
      uint4 w;
      w.x = ((u.x << 16) | (u.x >> 16)) ^ 0x80000000u;
      w.y = ((u.y << 16) | (u.y >> 16)) ^ 0x80000000u;
      w.z = ((u.z << 16) | (u.z >> 16)) ^ 0x80000000u;
      w.w = ((u.w << 16) | (u.w >> 16)) ^ 0x80000000u;
      aRe[rt][s] = __builtin_bit_cast(bf16x8, u);
      aIm[rt][s] = __builtin_bit_cast(bf16x8, w);
    }
  }

  float den[8];
  float num[8][6];
#pragma unroll
  for (int r = 0; r < 8; ++r) {
    den[r] = 0.f;
#pragma unroll
    for (int q = 0; q < 6; ++q) num[r][q] = 0.f;
  }

#pragma unroll 1
  for (int c = 0; c < NCHUNK; ++c) {
    const int jb = jbase0 + c * CHUNK;
    __syncthreads();
    // stage 64 keys (16KB) cooperatively, coalesced 16B per thread
#pragma unroll
    for (int r = 0; r < 4; ++r) {
      const int idx = r * 256 + tid;
      kbuf[(idx >> 4) * 17 + (idx & 15)] = Bk[(jb + (idx >> 4)) * 16 + (idx & 15)];
    }
    if (tid < 2 * CHUNK) vbuf[tid] = V4[jb * 2 + tid];
    __syncthreads();

#pragma unroll
    for (int ct = 0; ct < 4; ++ct) {
      const int keyl = ct * 16 + col;
      bf16x8 bfr[4];
#pragma unroll
      for (int s = 0; s < 4; ++s)
        bfr[s] = __builtin_bit_cast(bf16x8, kbuf[keyl * 17 + s * 4 + quad]);
      const float4 v01 = vbuf[keyl * 2 + 0];
      const float4 v23 = vbuf[keyl * 2 + 1];
      const float vv[6] = {v01.x, v01.y, v01.z, v01.w, v23.x, v23.y};
#pragma unroll
      for (int rt = 0; rt < 2; ++rt) {
        f32x4 aR = {0.f, 0.f, 0.f, 0.f};
        f32x4 aI = {0.f, 0.f, 0.f, 0.f};
#pragma unroll
        for (int s = 0; s < 4; ++s) {
          aR = __builtin_amdgcn_mfma_f32_16x16x32_bf16(aRe[rt][s], bfr[s], aR, 0, 0, 0);
          aI = __builtin_amdgcn_mfma_f32_16x16x32_bf16(aIm[rt][s], bfr[s], aI, 0, 0, 0);
        }
#pragma unroll
        for (int r = 0; r < 4; ++r) {
          const float f = aR[r] * aR[r] + aI[r] * aI[r];
          const float w = __expf(f);
          const int rr = rt * 4 + r;
          den[rr] += w;
#pragma unroll
          for (int q = 0; q < 6; ++q) num[rr][q] = fmaf(w, vv[q], num[rr][q]);
        }
      }
    }
  }

  // reduce across the 16 lanes (same rows, different cols) of each quad-group
#pragma unroll
  for (int rr = 0; rr < 8; ++rr) {
#pragma unroll
    for (int off = 1; off < 16; off <<= 1) {
      den[rr] += __shfl_xor(den[rr], off, 64);
#pragma unroll
      for (int q = 0; q < 6; ++q) num[rr][q] += __shfl_xor(num[rr][q], off, 64);
    }
  }

  if (col == 0) {
#pragma unroll
    for (int rt = 0; rt < 2; ++rt) {
#pragma unroll
      for (int r = 0; r < 4; ++r) {
        const int row = ibase + rt * 16 + quad * 4 + r;
        float* p = part + ((size_t)(js * NT + row)) * 8;
        const int rr = rt * 4 + r;
#pragma unroll
        for (int q = 0; q < 6; ++q) p[q] = num[rr][q];
        p[6] = den[rr];
      }
    }
  }
}

// ---------------------------------------------------------------------------
// Kernel 3: combine the 16 j-slice partials, normalize, emit float32.
// ---------------------------------------------------------------------------
__global__ __launch_bounds__(256) void combine_kernel(
    const float* __restrict__ part, float* __restrict__ out)
{
  const int row = blockIdx.x * 256 + threadIdx.x;
  float acc[7] = {0.f, 0.f, 0.f, 0.f, 0.f, 0.f, 0.f};
#pragma unroll
  for (int js = 0; js < JSPLIT; ++js) {
    const float* p = part + ((size_t)(js * NT + row)) * 8;
#pragma unroll
    for (int q = 0; q < 7; ++q) acc[q] += p[q];
  }
  const float inv = 1.0f / acc[6];
#pragma unroll
  for (int q = 0; q < 6; ++q)
    out[row * 6 + q] = acc[q] * inv;
}

// ---------------------------------------------------------------------------
// Workspace layout (bytes):
//   Are  @ 0        : 8192*64*4 = 2 MiB   (bf16 pairs packed in u32)
//   Bk   @ 2 MiB    : 2 MiB
//   V    @ 4 MiB    : 8192*8*4 = 256 KiB  (fp32, padded to 8)
//   part @ 4.25 MiB : 16*8192*8*4 = 4 MiB
//   total 8.25 MiB
// ---------------------------------------------------------------------------
extern "C" void kernel_launch(void* const* d_in, const int* in_sizes, int n_in,
                              void* d_out, int out_size, void* d_ws, size_t ws_size,
                              hipStream_t stream) {
  const float* x  = (const float*)d_in[0];
  const float* pq = (const float*)d_in[1];
  const float* pk = (const float*)d_in[2];
  const float* pv = (const float*)d_in[3];
  char* ws = (char*)d_ws;
  unsigned int* Are = (unsigned int*)(ws);
  unsigned int* Bk  = (unsigned int*)(ws + (size_t)(2u << 20));
  float*        V   = (float*)(ws + (size_t)(4u << 20));
  float*        prt = (float*)(ws + (size_t)(4u << 20) + (size_t)(256u << 10));

  prep_kernel<<<(NT * 3) / 4, 256, 0, stream>>>(x, pq, pk, pv, Are, Bk, (float4*)V);
  attn_kernel<<<NBI * JSPLIT, 256, 0, stream>>>((const uint4*)Are, (const uint4*)Bk,
                                                (const float4*)V, prt);
  combine_kernel<<<NT / 256, 256, 0, stream>>>(prt, (float*)d_out);
}

// Round 4
// 129.549 us; speedup vs baseline: 2.8344x; 2.8344x over previous
//
#include <hip/hip_runtime.h>
#include <hip/hip_bf16.h>

// Problem constants
#define NT 8192            // tokens
#define NQB 6              // qubits
#define NL 2               // layers
// Attention kernel tiling
#define JSPLIT 16
#define JSLICE (NT / JSPLIT)     // 512 keys per block
#define CHUNK 64                 // keys staged per LDS chunk
#define NCHUNK (JSLICE / CHUNK)  // 8
#define IPW 32                   // query rows per wave (2 rowtiles of 16)
#define WPB 4                    // waves per block
#define IPB (IPW * WPB)          // 128 rows per block
#define NBI (NT / IPB)           // 64 i-blocks

typedef __bf16 bf16x8 __attribute__((ext_vector_type(8)));
typedef float f32x4 __attribute__((ext_vector_type(4)));

static __device__ __forceinline__ unsigned int pack_bf2(float a, float b) {
  unsigned short lo = __builtin_bit_cast(unsigned short, __float2bfloat16(a));
  unsigned short hi = __builtin_bit_cast(unsigned short, __float2bfloat16(b));
  return (unsigned int)lo | ((unsigned int)hi << 16);
}

// one CNOT's index map: src(p) = p ^ (bit_c(p) ? mask_t : 0)  (an involution)
static __device__ __forceinline__ int cnot_src(int p, int q) {
  const int mc = 1 << (5 - q);
  const int mt = 1 << (5 - ((q + 1) % NQB));
  return (p & mc) ? (p ^ mt) : p;
}

// ---------------------------------------------------------------------------
// Kernel 1: statevector prep, product-state form (verified round 3, absmax ok).
// One wave per (token, set); lane = basis state.
// ---------------------------------------------------------------------------
__global__ __launch_bounds__(256) void prep_kernel(
    const float* __restrict__ x, const float* __restrict__ pq,
    const float* __restrict__ pk, const float* __restrict__ pv,
    unsigned int* __restrict__ Are, unsigned int* __restrict__ Bk,
    float4* __restrict__ V4)
{
  const int wid  = blockIdx.x * 4 + (threadIdx.x >> 6);
  const int lane = threadIdx.x & 63;
  const int set  = wid >> 13;          // / 8192
  const int tok  = wid & (NT - 1);
  const float* pp = (set == 0) ? pq : ((set == 1) ? pk : pv);

  // sigma(l) = src_0(src_1(...src_5(l)))   [final[l] = old[sigma(l)]]
  int m = lane;
#pragma unroll
  for (int q = 5; q >= 0; --q) m = cnot_src(m, q);
  // sigma^{-1}(l) = src_5(src_4(...src_0(l)))
  int inv = lane;
#pragma unroll
  for (int q = 0; q < 6; ++q) inv = cnot_src(inv, q);

  // product state (through layer-0) evaluated at index m
  float R = 1.f, phi = 0.f;
#pragma unroll
  for (int q = 0; q < 6; ++q) {
    float s, c;
    __sincosf(0.5f * (x[tok * NQB + q] + pp[q * 2 + 0]), &s, &c);
    const float bh = 0.5f * pp[q * 2 + 1];
    if ((m >> (5 - q)) & 1) { R *= s; phi += bh; }
    else                    { R *= c; phi -= bh; }
  }
  float sp, cp;
  __sincosf(phi, &sp, &cp);
  float re = R * cp, im = R * sp;

  // layer-1 RYs (entangled now -> shuffles)
#pragma unroll
  for (int q = 0; q < 6; ++q) {
    const int mask = 1 << (5 - q);
    float s, c;
    __sincosf(0.5f * pp[2 * NQB + q * 2 + 0], &s, &c);
    const float pre = __shfl_xor(re, mask, 64);
    const float pim = __shfl_xor(im, mask, 64);
    const float se = (lane & mask) ? s : -s;
    re = fmaf(se, pre, c * re);
    im = fmaf(se, pim, c * im);
  }
  // layer-1 RZs combined into one phase per lane
  float phi2 = 0.f;
#pragma unroll
  for (int q = 0; q < 6; ++q) {
    const float bh = 0.5f * pp[2 * NQB + q * 2 + 1];
    phi2 += (lane & (1 << (5 - q))) ? bh : -bh;
  }
  float s2, c2;
  __sincosf(phi2, &s2, &c2);
  const float fre = re * c2 - im * s2;
  const float fim = re * s2 + im * c2;

  if (set == 0) {
    Are[tok * 64 + inv] = pack_bf2(fre, fim);     // [qr, qi]
  } else if (set == 1) {
    Bk[tok * 64 + inv] = pack_bf2(fre, fim);      // [kr, ki]
  } else {
    const float prob = fre * fre + fim * fim;     // prob of final basis index 'inv'
    float vq[NQB];
#pragma unroll
    for (int q = 0; q < NQB; ++q) {
      float v = (inv & (1 << (5 - q))) ? -prob : prob;  // sign = 1-2*bit
#pragma unroll
      for (int off = 1; off < 64; off <<= 1) v += __shfl_xor(v, off, 64);
      vq[q] = v;
    }
    if (lane == 0) {
      V4[tok * 2 + 0] = make_float4(vq[0], vq[1], vq[2], vq[3]);
      V4[tok * 2 + 1] = make_float4(vq[4], vq[5], 0.f, 0.f);
    }
  }
}

// ---------------------------------------------------------------------------
// Kernel 2: fused swap-test attention.
//  - block: 4 waves x 32 query rows = 128 rows; grid = 64 i-blocks x 16 j-slices
//    (1024 blocks = 4 blocks/CU at runtime; VGPR ~112 -> 4 waves/SIMD fits)
//  - launch_bounds min-waves kept at 2: round-3's (256,4) clamped VGPRs to 64
//    and spilled 1.2 GB/dispatch to scratch. Runtime occupancy is set by the
//    ACTUAL VGPR count (112*4=448<=512), not by the launch_bounds hint.
//  - f = Re^2+Im^2 in [0,1] => softmax needs no max-shift; w = exp(f)
// MFMA 16x16x32 bf16 layouts:
//   A: row = lane&15, k = (lane>>4)*8 + j
//   B: col = lane&15, k = (lane>>4)*8 + j
//   D: col = lane&15, row = (lane>>4)*4 + reg
// ---------------------------------------------------------------------------
__global__ __launch_bounds__(256, 2) void attn_kernel(
    const uint4* __restrict__ Are, const uint4* __restrict__ Bk,
    const float4* __restrict__ V4, float* __restrict__ part)
{
  __shared__ uint4 kbuf[CHUNK * 17];   // row stride 17 uint4 = 272B
  __shared__ float4 vbuf[CHUNK * 2];   // 8 floats per key (6 used)

  const int tid  = threadIdx.x;
  const int lane = tid & 63;
  const int wave = tid >> 6;
  const int col  = lane & 15;
  const int quad = lane >> 4;

  const int ib = blockIdx.x & (NBI - 1);
  const int js = blockIdx.x / NBI;
  const int ibase = ib * IPB + wave * IPW;
  const int jbase0 = js * JSLICE;

  // A fragments for this wave's 32 rows, kept in registers for the whole sweep.
  // aIm derived in-register: (qr,qi) -> (qi,-qr) per packed u32.
  bf16x8 aRe[2][4], aIm[2][4];
#pragma unroll
  for (int rt = 0; rt < 2; ++rt) {
    const int row = ibase + rt * 16 + col;
    const uint4* pr = Are + row * 16 + quad;   // row = 16 uint4 (256B)
#pragma unroll
    for (int s = 0; s < 4; ++s) {
      const uint4 u = pr[s * 4];
      uint4 w;
      w.x = ((u.x << 16) | (u.x >> 16)) ^ 0x80000000u;
      w.y = ((u.y << 16) | (u.y >> 16)) ^ 0x80000000u;
      w.z = ((u.z << 16) | (u.z >> 16)) ^ 0x80000000u;
      w.w = ((u.w << 16) | (u.w >> 16)) ^ 0x80000000u;
      aRe[rt][s] = __builtin_bit_cast(bf16x8, u);
      aIm[rt][s] = __builtin_bit_cast(bf16x8, w);
    }
  }

  float den[8];
  float num[8][6];
#pragma unroll
  for (int r = 0; r < 8; ++r) {
    den[r] = 0.f;
#pragma unroll
    for (int q = 0; q < 6; ++q) num[r][q] = 0.f;
  }

#pragma unroll 1
  for (int c = 0; c < NCHUNK; ++c) {
    const int jb = jbase0 + c * CHUNK;
    __syncthreads();
    // stage 64 keys (16KB) cooperatively, coalesced 16B per thread
#pragma unroll
    for (int r = 0; r < 4; ++r) {
      const int idx = r * 256 + tid;
      kbuf[(idx >> 4) * 17 + (idx & 15)] = Bk[(jb + (idx >> 4)) * 16 + (idx & 15)];
    }
    if (tid < 2 * CHUNK) vbuf[tid] = V4[jb * 2 + tid];
    __syncthreads();

#pragma unroll
    for (int ct = 0; ct < 4; ++ct) {
      const int keyl = ct * 16 + col;
      bf16x8 bfr[4];
#pragma unroll
      for (int s = 0; s < 4; ++s)
        bfr[s] = __builtin_bit_cast(bf16x8, kbuf[keyl * 17 + s * 4 + quad]);
      const float4 v01 = vbuf[keyl * 2 + 0];
      const float4 v23 = vbuf[keyl * 2 + 1];
      const float vv[6] = {v01.x, v01.y, v01.z, v01.w, v23.x, v23.y};
#pragma unroll
      for (int rt = 0; rt < 2; ++rt) {
        f32x4 aR = {0.f, 0.f, 0.f, 0.f};
        f32x4 aI = {0.f, 0.f, 0.f, 0.f};
#pragma unroll
        for (int s = 0; s < 4; ++s) {
          aR = __builtin_amdgcn_mfma_f32_16x16x32_bf16(aRe[rt][s], bfr[s], aR, 0, 0, 0);
          aI = __builtin_amdgcn_mfma_f32_16x16x32_bf16(aIm[rt][s], bfr[s], aI, 0, 0, 0);
        }
#pragma unroll
        for (int r = 0; r < 4; ++r) {
          const float f = aR[r] * aR[r] + aI[r] * aI[r];
          const float w = __expf(f);
          const int rr = rt * 4 + r;
          den[rr] += w;
#pragma unroll
          for (int q = 0; q < 6; ++q) num[rr][q] = fmaf(w, vv[q], num[rr][q]);
        }
      }
    }
  }

  // reduce across the 16 lanes (same rows, different cols) of each quad-group
#pragma unroll
  for (int rr = 0; rr < 8; ++rr) {
#pragma unroll
    for (int off = 1; off < 16; off <<= 1) {
      den[rr] += __shfl_xor(den[rr], off, 64);
#pragma unroll
      for (int q = 0; q < 6; ++q) num[rr][q] += __shfl_xor(num[rr][q], off, 64);
    }
  }

  if (col == 0) {
#pragma unroll
    for (int rt = 0; rt < 2; ++rt) {
#pragma unroll
      for (int r = 0; r < 4; ++r) {
        const int row = ibase + rt * 16 + quad * 4 + r;
        float* p = part + ((size_t)(js * NT + row)) * 8;
        const int rr = rt * 4 + r;
#pragma unroll
        for (int q = 0; q < 6; ++q) p[q] = num[rr][q];
        p[6] = den[rr];
      }
    }
  }
}

// ---------------------------------------------------------------------------
// Kernel 3: combine the 16 j-slice partials, normalize, emit float32.
// ---------------------------------------------------------------------------
__global__ __launch_bounds__(256) void combine_kernel(
    const float* __restrict__ part, float* __restrict__ out)
{
  const int row = blockIdx.x * 256 + threadIdx.x;
  float acc[7] = {0.f, 0.f, 0.f, 0.f, 0.f, 0.f, 0.f};
#pragma unroll
  for (int js = 0; js < JSPLIT; ++js) {
    const float* p = part + ((size_t)(js * NT + row)) * 8;
#pragma unroll
    for (int q = 0; q < 7; ++q) acc[q] += p[q];
  }
  const float inv = 1.0f / acc[6];
#pragma unroll
  for (int q = 0; q < 6; ++q)
    out[row * 6 + q] = acc[q] * inv;
}

// ---------------------------------------------------------------------------
// Workspace layout (bytes):
//   Are  @ 0        : 8192*64*4 = 2 MiB   (bf16 pairs packed in u32)
//   Bk   @ 2 MiB    : 2 MiB
//   V    @ 4 MiB    : 8192*8*4 = 256 KiB  (fp32, padded to 8)
//   part @ 4.25 MiB : 16*8192*8*4 = 4 MiB
//   total 8.25 MiB
// ---------------------------------------------------------------------------
extern "C" void kernel_launch(void* const* d_in, const int* in_sizes, int n_in,
                              void* d_out, int out_size, void* d_ws, size_t ws_size,
                              hipStream_t stream) {
  const float* x  = (const float*)d_in[0];
  const float* pq = (const float*)d_in[1];
  const float* pk = (const float*)d_in[2];
  const float* pv = (const float*)d_in[3];
  char* ws = (char*)d_ws;
  unsigned int* Are = (unsigned int*)(ws);
  unsigned int* Bk  = (unsigned int*)(ws + (size_t)(2u << 20));
  float*        V   = (float*)(ws + (size_t)(4u << 20));
  float*        prt = (float*)(ws + (size_t)(4u << 20) + (size_t)(256u << 10));

  prep_kernel<<<(NT * 3) / 4, 256, 0, stream>>>(x, pq, pk, pv, Are, Bk, (float4*)V);
  attn_kernel<<<NBI * JSPLIT, 256, 0, stream>>>((const uint4*)Are, (const uint4*)Bk,
                                                (const float4*)V, prt);
  combine_kernel<<<NT / 256, 256, 0, stream>>>(prt, (float*)d_out);
}